// Round 3
// baseline (741.839 us; speedup 1.0000x reference)
//
#include <hip/hip_runtime.h>
#include <hip/hip_bf16.h>

typedef float f32x4 __attribute__((ext_vector_type(4)));
typedef short s16x8 __attribute__((ext_vector_type(8)));

#define N_NODES 50176

static __device__ __forceinline__ ushort f2bf(float x) {
    __hip_bfloat16 h = __float2bfloat16(x);
    return *reinterpret_cast<ushort*>(&h);
}
static __device__ __forceinline__ float bf2f(ushort u) {
    __hip_bfloat16 h = *reinterpret_cast<__hip_bfloat16*>(&u);
    return __bfloat162float(h);
}

static __device__ __forceinline__ void gload_lds16(const void* g, void* l) {
    __builtin_amdgcn_global_load_lds((const __attribute__((address_space(1))) void*)g,
                                     (__attribute__((address_space(3))) void*)l, 16, 0, 0);
}

// ---------------- prep 0: Bt2[512][1024], Bt3[512][512], decLast; zero accumulators ----------------
// (runs BEFORE k_front; Bt1 is built AFTER k_front so 1/alpha_sum can be folded into W1rel)
__global__ void k_prep0(const float* W2r, const float* W2t, const float* decW,
                        ushort* Bt2, ushort* Bt3, float* decLast, float* alpha_sum, float* bn_acc) {
    int idx = blockIdx.x * 256 + threadIdx.x;
    if (idx < 512 * 1024) {                // Bt2[j][k]: k<512 -> W2rel[k][j], else W2root[k-512][j]
        int j = idx >> 10, k = idx & 1023;
        float v = (k < 512) ? W2r[k * 512 + j] : W2t[(k - 512) * 512 + j];
        Bt2[idx] = f2bf(v);
    }
    if (idx < 512 * 512) {                 // Bt3[j][k] = decW(k, j)
        int j = idx >> 9, k = idx & 511;
        Bt3[idx] = f2bf(decW[k * 512 + j]);
    }
    if (idx < 512) decLast[idx] = decW[512 * 512 + idx];
    if (idx < 2048) bn_acc[idx] = 0.f;
    if (idx == 0) alpha_sum[0] = 0.f;
}

// ---------------- prep 1: Bt1[512][2048] = [s*W1rel; W1root]^T with s = 1/(alpha_sum+1e-8) ----------------
// The layer-1 aggregation is stored UNSCALED by k_front; linearity lets us fold the global
// softmax denominator into the weight matrix instead: (s*aggU)@W1rel == aggU@(s*W1rel).
__global__ void k_prep1(const float* W1r, const float* W1t, const float* asum, ushort* Bt1) {
    int idx = blockIdx.x * 256 + threadIdx.x;   // exactly 512*2048 threads
    int j = idx >> 11, k = idx & 2047;
    float s = 1.f / (asum[0] + 1e-8f);
    float v = (k < 1024) ? W1r[k * 512 + j] * s : W1t[(k - 1024) * 512 + j];
    Bt1[idx] = f2bf(v);
}

// ---------------- fused front: NCHW->bf16 transpose + coords + edges/node_w + UNSCALED layer-1 agg ----------------
__global__ __launch_bounds__(256) void k_front(const float* __restrict__ vis, const float* __restrict__ tac,
                                               const float* __restrict__ projW, const float* __restrict__ projb,
                                               ushort* __restrict__ xcat1, float* __restrict__ ew_exp,
                                               float* __restrict__ node_w, float* __restrict__ alpha_sum) {
    int b = blockIdx.x, tid = threadIdx.x;
    __shared__ ushort tile[128 * 50];
    __shared__ float pw[2048];
    __shared__ float cx[52], cy[52], ea[84], eex[84], wsum[4];
    __shared__ float wl[49], wt[49];
    for (int p = tid; p < 2048; p += 256) pw[p] = projW[p];
    float a0t = 0.f, a1t = 0.f;
    const int cn = tid >> 2, dl = tid & 3;
    for (int chunk = 0; chunk < 8; ++chunk) {
        __syncthreads();                   // protect tile (and pw on first iter)
        const float* src = (chunk < 4 ? vis : tac) + ((size_t)b * 512 + (chunk & 3) * 128) * 49;
        for (int p = tid; p < 128 * 49; p += 256) {
            int d = p / 49, n = p - d * 49;
            tile[d * 50 + n] = f2bf(src[p]);
        }
        __syncthreads();
        for (int p = tid; p < 49 * 64; p += 256) {
            int n = p >> 6, d2 = (p & 63) * 2;
            ushort2 o;
            o.x = tile[d2 * 50 + n];
            o.y = tile[(d2 + 1) * 50 + n];
            *(ushort2*)&xcat1[((size_t)(b * 49 + n)) * 2048 + 1024 + chunk * 128 + d2] = o;
        }
        if (tid < 196) {
#pragma unroll 4
            for (int j = 0; j < 32; ++j) {
                int d = dl + 4 * j;
                float v = bf2f(tile[d * 50 + cn]);
                int gd = chunk * 128 + d;
                a0t += v * pw[2 * gd];
                a1t += v * pw[2 * gd + 1];
            }
        }
    }
    a0t += __shfl_down(a0t, 1); a1t += __shfl_down(a1t, 1);
    a0t += __shfl_down(a0t, 2); a1t += __shfl_down(a1t, 2);
    if (tid < 196 && dl == 0) { cx[cn] = a0t + projb[0]; cy[cn] = a1t + projb[1]; }
    __syncthreads();
    float ex = 0.f;
    if (tid < 84) {
        int s, d2;
        if (tid < 42) { int r = tid / 6, c = tid - r * 6; s = r * 7 + c; d2 = s + 1; }
        else { int t = tid - 42; int r = t / 7, c = t - r * 7; s = r * 7 + c; d2 = s + 7; }
        float dx = cx[s] - cx[d2], dy = cy[s] - cy[d2];
        float dist = sqrtf(dx * dx + dy * dy);
        float attr = 1.f / (1.f + expf(-(1.f / (dist + 1e-6f))));
        ea[tid] = attr;
        ex = expf(attr);
        eex[tid] = ex;
        ew_exp[b * 84 + tid] = ex;
    }
    for (int off = 32; off; off >>= 1) ex += __shfl_down(ex, off);
    if ((tid & 63) == 0) wsum[tid >> 6] = ex;
    __syncthreads();
    if (tid == 0) atomicAdd(alpha_sum, wsum[0] + wsum[1] + wsum[2] + wsum[3]);
    if (tid < 49) {
        int r = tid / 7, c = tid - r * 7;
        float s = 0.f; int cnt = 0;
        if (c > 0) { s += ea[r * 6 + c - 1]; cnt++; }
        if (c < 6) { s += ea[r * 6 + c]; cnt++; }
        if (r > 0) { s += ea[42 + (r - 1) * 7 + c]; cnt++; }
        if (r < 6) { s += ea[42 + r * 7 + c]; cnt++; }
        node_w[b * 49 + tid] = s / (float)cnt;
        // unscaled in-edge weights / deg for the fused agg below
        int deg = (c > 0) + (r > 0);
        float inv = deg ? 1.f / (float)deg : 0.f;
        wl[tid] = (c > 0) ? eex[r * 6 + c - 1] * inv : 0.f;
        wt[tid] = (r > 0) ? eex[42 + (r - 1) * 7 + c] * inv : 0.f;
    }
    __syncthreads();   // wl/wt visible; all node-half global writes drained (vmcnt(0) at barrier)
    // ---- fused layer-1 aggregation (UNSCALED by 1/alpha_sum; folded into Bt1 by k_prep1) ----
    // reads the node halves this block just wrote (L1/L2-hot), writes agg cols [0..1024)
    ushort* base = xcat1 + (size_t)b * 49 * 2048;
    for (int idx = tid; idx < 49 * 128; idx += 256) {
        int n = idx >> 7, ch = idx & 127;
        float w1 = wl[n], w2 = wt[n];
        float acc[8];
#pragma unroll
        for (int k = 0; k < 8; ++k) acc[k] = 0.f;
        if (w1 != 0.f) {
            s16x8 u = *(const s16x8*)(base + (size_t)(n - 1) * 2048 + 1024 + ch * 8);
#pragma unroll
            for (int k = 0; k < 8; ++k) acc[k] += w1 * bf2f((ushort)u[k]);
        }
        if (w2 != 0.f) {
            s16x8 u = *(const s16x8*)(base + (size_t)(n - 7) * 2048 + 1024 + ch * 8);
#pragma unroll
            for (int k = 0; k < 8; ++k) acc[k] += w2 * bf2f((ushort)u[k]);
        }
        s16x8 o;
#pragma unroll
        for (int k = 0; k < 8; ++k) o[k] = (short)f2bf(acc[k]);
        *(s16x8*)(base + (size_t)n * 2048 + ch * 8) = o;
    }
}

// ---------------- bf16 MFMA GEMM: C[M][512] = A[M][K] @ Bt[512][K]^T ----------------
// 128x128 tile, BK=32, global_load_lds width=16 staging, unpadded LDS.
// XCD swizzle: bid = g*32 + colb*8 + s -> rowb = g*8+s, colb. The 4 blocks sharing an
// A-slab have equal bid%8 (same XCD under round-robin dispatch) -> A hits that XCD's L2.
template <int EPI>
__global__ __launch_bounds__(256, 2)
void k_gemm(const ushort* __restrict__ A, const ushort* __restrict__ Bt, float* __restrict__ C,
            int K,
            const float* __restrict__ bias, float* __restrict__ bn_sum, float* __restrict__ bn_sumsq,
            const float* __restrict__ node_w, const float* __restrict__ decLast,
            const float* __restrict__ decb, float* __restrict__ out) {
    __shared__ __align__(16) ushort As[128 * 32];
    __shared__ __align__(16) ushort Bs[128 * 32];
    const int bid = blockIdx.x;
    const int rowb = ((bid & 7) | ((bid >> 5) << 3));
    const int colb = (bid >> 3) & 3;
    const int row0 = rowb << 7, col0 = colb << 7;
    const int tid = threadIdx.x;
    const int lane = tid & 63, wave = tid >> 6;
    const int wm = (wave & 1) << 6, wn = (wave >> 1) << 6;
    const int quad = lane >> 4, l16 = lane & 15;
    const int K8 = K >> 3;

    const uint4* Ag = (const uint4*)A;
    const uint4* Bg = (const uint4*)Bt;

    // wave w stages chunks w and w+4 of both A and B
    const int c0 = wave, c1 = wave + 4;
    const int lrow = lane >> 2, lkc = lane & 3;
    const size_t iA0 = (size_t)(row0 + c0 * 16 + lrow) * K8 + lkc;
    const size_t iA1 = (size_t)(row0 + c1 * 16 + lrow) * K8 + lkc;
    const size_t iB0 = (size_t)(col0 + c0 * 16 + lrow) * K8 + lkc;
    const size_t iB1 = (size_t)(col0 + c1 * 16 + lrow) * K8 + lkc;
    ushort* lA0 = As + c0 * 512;   // wave-uniform LDS bases (512 ushorts = 1KB per chunk)
    ushort* lA1 = As + c1 * 512;
    ushort* lB0 = Bs + c0 * 512;
    ushort* lB1 = Bs + c1 * 512;

    f32x4 acc[4][4];
#pragma unroll
    for (int i = 0; i < 4; ++i)
#pragma unroll
        for (int j = 0; j < 4; ++j) acc[i][j] = (f32x4)0.f;

    const int nk = K >> 5;
    for (int kt = 0; kt < nk; ++kt) {
        const size_t o = (size_t)kt * 4;
        gload_lds16(Ag + iA0 + o, lA0);
        gload_lds16(Ag + iA1 + o, lA1);
        gload_lds16(Bg + iB0 + o, lB0);
        gload_lds16(Bg + iB1 + o, lB1);
        __syncthreads();
        s16x8 af[4], bf[4];
#pragma unroll
        for (int i = 0; i < 4; ++i) af[i] = *(const s16x8*)&As[(wm + i * 16 + l16) * 32 + quad * 8];
#pragma unroll
        for (int j = 0; j < 4; ++j) bf[j] = *(const s16x8*)&Bs[(wn + j * 16 + l16) * 32 + quad * 8];
#pragma unroll
        for (int i = 0; i < 4; ++i)
#pragma unroll
            for (int j = 0; j < 4; ++j)
                acc[i][j] = __builtin_amdgcn_mfma_f32_16x16x32_bf16(af[i], bf[j], acc[i][j], 0, 0, 0);
        __syncthreads();
    }

    if (EPI == 0) {
#pragma unroll
        for (int j = 0; j < 4; ++j) {
            int col = col0 + wn + j * 16 + l16;
            float bcol = bias[col];
            float s = 0.f, s2 = 0.f;
#pragma unroll
            for (int i = 0; i < 4; ++i) {
#pragma unroll
                for (int r = 0; r < 4; ++r) {
                    int m = row0 + wm + i * 16 + quad * 4 + r;
                    float v = acc[i][j][r] + bcol;
                    C[(size_t)m * 512 + col] = v;
                    s += v; s2 += v * v;
                }
            }
            s += __shfl_xor(s, 16); s += __shfl_xor(s, 32);
            s2 += __shfl_xor(s2, 16); s2 += __shfl_xor(s2, 32);
            if (quad == 0) { atomicAdd(&bn_sum[col], s); atomicAdd(&bn_sumsq[col], s2); }
        }
    } else {
#pragma unroll
        for (int i = 0; i < 4; ++i) {
#pragma unroll
            for (int j = 0; j < 4; ++j) {
#pragma unroll
                for (int r = 0; r < 4; ++r) {
                    int m = row0 + wm + i * 16 + quad * 4 + r;
                    int n = col0 + wn + j * 16 + l16;
                    float v = acc[i][j][r];
                    v += node_w[m] * decLast[n] + decb[n];
                    v = fmaxf(v, 0.f);
                    int bb = m / 49, sp = m - bb * 49;
                    out[((size_t)bb * 512 + n) * 49 + sp] = v;   // (B,512,7,7)
                }
            }
        }
    }
}

// ---------------- fused BN-stat + BN-apply + relu + cast + in-neighbor aggregation; emits next GEMM A=[agg|x] ----------------
__global__ __launch_bounds__(256) void k_bnagg(const float* __restrict__ P, const float* __restrict__ ew,
                                               const float* __restrict__ asum,
                                               const float* __restrict__ bn_sum, const float* __restrict__ bn_sumsq,
                                               const float* __restrict__ gamma, const float* __restrict__ beta,
                                               ushort* __restrict__ xcat) {
    int b = blockIdx.x, tid = threadIdx.x;
    __shared__ ushort xl[49 * 512];
    __shared__ float wl[49], wt[49];
    __shared__ float scl_s[512], shf_s[512];
    const float invN = 1.f / (float)N_NODES;
    for (int d = tid; d < 512; d += 256) {     // per-block redundant BN stat (8 KB L2-hot reads)
        float mu = bn_sum[d] * invN;
        float var = bn_sumsq[d] * invN - mu * mu;
        float sc = gamma[d] * rsqrtf(var + 1e-5f);
        scl_s[d] = sc;
        shf_s[d] = beta[d] - mu * sc;
    }
    if (tid < 49) {
        int r = tid / 7, c = tid - r * 7;
        int deg = (c > 0) + (r > 0);
        float sc = deg ? (1.f / (asum[0] + 1e-8f)) / (float)deg : 0.f;
        wl[tid] = (c > 0) ? ew[b * 84 + r * 6 + (c - 1)] * sc : 0.f;
        wt[tid] = (r > 0) ? ew[b * 84 + 42 + (r - 1) * 7 + c] * sc : 0.f;
    }
    __syncthreads();
    int dc = tid & 127;                 // fixed 4-col chunk per thread
    int sp0 = tid >> 7;
    float4 scl = ((const float4*)scl_s)[dc];
    float4 shf = ((const float4*)shf_s)[dc];
    for (int sp = sp0; sp < 49; sp += 2) {
        float4 v = ((const float4*)(P + ((size_t)b * 49 + sp) * 512))[dc];
        ushort4 o;
        o.x = f2bf(fmaxf(v.x * scl.x + shf.x, 0.f));
        o.y = f2bf(fmaxf(v.y * scl.y + shf.y, 0.f));
        o.z = f2bf(fmaxf(v.z * scl.z + shf.z, 0.f));
        o.w = f2bf(fmaxf(v.w * scl.w + shf.w, 0.f));
        *(ushort4*)&xl[sp * 512 + dc * 4] = o;
        ((ushort4*)(xcat + ((size_t)b * 49 + sp) * 1024 + 512))[dc] = o;
    }
    __syncthreads();
    for (int sp = sp0; sp < 49; sp += 2) {
        float a0 = 0.f, a1 = 0.f, a2 = 0.f, a3 = 0.f;
        float w1 = wl[sp], w2 = wt[sp];
        if (w1 != 0.f) {
            ushort4 u = *(const ushort4*)&xl[(sp - 1) * 512 + dc * 4];
            a0 += w1 * bf2f(u.x); a1 += w1 * bf2f(u.y); a2 += w1 * bf2f(u.z); a3 += w1 * bf2f(u.w);
        }
        if (w2 != 0.f) {
            ushort4 u = *(const ushort4*)&xl[(sp - 7) * 512 + dc * 4];
            a0 += w2 * bf2f(u.x); a1 += w2 * bf2f(u.y); a2 += w2 * bf2f(u.z); a3 += w2 * bf2f(u.w);
        }
        ushort4 o;
        o.x = f2bf(a0); o.y = f2bf(a1); o.z = f2bf(a2); o.w = f2bf(a3);
        ((ushort4*)(xcat + ((size_t)b * 49 + sp) * 1024))[dc] = o;
    }
}

// ---------------- fused BN-stat + BN apply + relu + bf16 cast (per-graph blocks; feeds dec GEMM) ----------------
__global__ __launch_bounds__(256) void k_bnapply(const float* __restrict__ x,
                                                 const float* __restrict__ bn_sum, const float* __restrict__ bn_sumsq,
                                                 const float* __restrict__ gamma, const float* __restrict__ beta,
                                                 ushort* __restrict__ xb) {
    int b = blockIdx.x, tid = threadIdx.x;
    __shared__ float scl_s[512], shf_s[512];
    const float invN = 1.f / (float)N_NODES;
    for (int d = tid; d < 512; d += 256) {
        float mu = bn_sum[d] * invN;
        float var = bn_sumsq[d] * invN - mu * mu;
        float sc = gamma[d] * rsqrtf(var + 1e-5f);
        scl_s[d] = sc;
        shf_s[d] = beta[d] - mu * sc;
    }
    __syncthreads();
    const float4* src = (const float4*)(x + (size_t)b * 49 * 512);
    ushort4* dst = (ushort4*)(xb + (size_t)b * 49 * 512);
    for (int idx = tid; idx < 49 * 128; idx += 256) {
        int dc = idx & 127;
        float4 scl = ((const float4*)scl_s)[dc];
        float4 shf = ((const float4*)shf_s)[dc];
        float4 v = src[idx];
        ushort4 o;
        o.x = f2bf(fmaxf(v.x * scl.x + shf.x, 0.f));
        o.y = f2bf(fmaxf(v.y * scl.y + shf.y, 0.f));
        o.z = f2bf(fmaxf(v.z * scl.z + shf.z, 0.f));
        o.w = f2bf(fmaxf(v.w * scl.w + shf.w, 0.f));
        dst[idx] = o;
    }
}

extern "C" void kernel_launch(void* const* d_in, const int* in_sizes, int n_in,
                              void* d_out, int out_size, void* d_ws, size_t ws_size,
                              hipStream_t stream) {
    const float* vis   = (const float*)d_in[0];
    const float* tac   = (const float*)d_in[1];
    const float* projW = (const float*)d_in[2];
    const float* projb = (const float*)d_in[3];
    const float* W1r   = (const float*)d_in[4];
    const float* b1    = (const float*)d_in[5];
    const float* W1t   = (const float*)d_in[6];
    const float* g1    = (const float*)d_in[7];
    const float* be1   = (const float*)d_in[8];
    const float* W2r   = (const float*)d_in[9];
    const float* b2    = (const float*)d_in[10];
    const float* W2t   = (const float*)d_in[11];
    const float* g2    = (const float*)d_in[12];
    const float* be2   = (const float*)d_in[13];
    const float* decW  = (const float*)d_in[14];
    const float* decb  = (const float*)d_in[15];
    float* out = (float*)d_out;

    char* p = (char*)d_ws;
    ushort* X   = (ushort*)p; p += 205520896;   // [N][2048] bf16; reused as xcat2 [N][1024] and x3b [N][512]
    float*  P   = (float*)p;  p += 102760448;   // [N][512] f32 GEMM out
    float* ew     = (float*)p; p += 344064;
    float* nw     = (float*)p; p += 200704;
    ushort* Bt1   = (ushort*)p; p += 2097152;   // [512][2048]
    ushort* Bt2   = (ushort*)p; p += 1048576;   // [512][1024]
    ushort* Bt3   = (ushort*)p; p += 524288;    // [512][512]
    float* decLast = (float*)p; p += 2048;
    float* asum   = (float*)p;  p += 256;
    float* bnacc  = (float*)p;  p += 4 * 512 * 4;
    float* bn1s = bnacc, *bn1q = bnacc + 512, *bn2s = bnacc + 1024, *bn2q = bnacc + 1536;

    ushort* xcat1 = X;          // [N][2048]: cols 0..1023 agg (UNSCALED), 1024..2047 node
    ushort* xcat2 = X;          // [N][1024]: cols 0..511 agg, 512..1023 x   (aliases; sequential use)
    ushort* x3b   = X;          // [N][512]

    k_prep0<<<2048, 256, 0, stream>>>(W2r, W2t, decW, Bt2, Bt3, decLast, asum, bnacc);
    k_front<<<1024, 256, 0, stream>>>(vis, tac, projW, projb, xcat1, ew, nw, asum);
    k_prep1<<<4096, 256, 0, stream>>>(W1r, W1t, asum, Bt1);

    k_gemm<0><<<392 * 4, 256, 0, stream>>>(xcat1, Bt1, P, 2048, b1, bn1s, bn1q, nullptr, nullptr, nullptr, nullptr);
    k_bnagg<<<1024, 256, 0, stream>>>(P, ew, asum, bn1s, bn1q, g1, be1, xcat2);

    k_gemm<0><<<392 * 4, 256, 0, stream>>>(xcat2, Bt2, P, 1024, b2, bn2s, bn2q, nullptr, nullptr, nullptr, nullptr);
    k_bnapply<<<1024, 256, 0, stream>>>(P, bn2s, bn2q, g2, be2, x3b);

    k_gemm<1><<<392 * 4, 256, 0, stream>>>(x3b, Bt3, nullptr, 512, nullptr, nullptr, nullptr, nw, decLast, decb, out);
}